// Round 4
// baseline (217.791 us; speedup 1.0000x reference)
//
#include <hip/hip_runtime.h>

#define NN 4096
#define DD 256
#define TEMP 0.07f
#define INV_T (1.0f / TEMP)
#define BLK 512
#define IB 64            // i-rows per block
#define JC 16            // j-chunks
#define JPC (NN / JC)    // 256 j per chunk
#define JT (JPC / 16)    // 16 j-tiles per chunk
#define GRID ((NN / IB) * JC)   // 1024 blocks
#define NSTAT (NN * 8)

typedef __attribute__((ext_vector_type(8))) short short8;
typedef __attribute__((ext_vector_type(4))) float f32x4;

__device__ __forceinline__ unsigned short f2bf(float x) {
    unsigned int b = __float_as_uint(x);
    return (unsigned short)((b + 0x7fffu + ((b >> 16) & 1u)) >> 16);
}

// ---------------- convert F f32 -> bf16, zero stats+counter ----------------
__global__ __launch_bounds__(256) void cvt_k(const float* __restrict__ F,
                                             unsigned short* __restrict__ Fb,
                                             float* __restrict__ gstats,
                                             unsigned int* __restrict__ counter) {
    int idx = blockIdx.x * 256 + threadIdx.x;   // 262144 threads
    float4 v = ((const float4*)F)[idx];
    ushort4 o;
    o.x = f2bf(v.x); o.y = f2bf(v.y); o.z = f2bf(v.z); o.w = f2bf(v.w);
    ((ushort4*)Fb)[idx] = o;
    if (idx < NSTAT) gstats[idx] = 0.f;
    if (idx == 0) *counter = 0u;
}

// ---------------- fused stats + last-block finalize ----------------
// 9-sum shift-free decomposition per row i (l=(s-1)/T):
// a=sum_same e^s, b=sum_diff e^s, e1/e2=sum e^l, f1/f2=sum e^l*e^s,
// g=sum_same l, h=sum_same l*e^s.
__global__ __launch_bounds__(BLK, 4) void supcon_k(const unsigned short* __restrict__ Fb,
                                                   const int* __restrict__ labels,
                                                   float* __restrict__ gstats,
                                                   unsigned int* __restrict__ counter,
                                                   float* __restrict__ out) {
    __shared__ unsigned short sFi[IB * DD];   // 32 KB, XOR-swizzled 16B cols
    __shared__ int slab[JPC];                 // 1 KB
    __shared__ int sdone;
    __shared__ int hist[16];
    __shared__ float sacc[8];
    float* sred = (float*)sFi;                // aliased after compute: [8][64][8]

    const int tid = threadIdx.x;
    const int lane = tid & 63;
    const int wid = tid >> 6;
    const int il = lane & 15;
    const int kg = lane >> 4;
    const int ib = blockIdx.x >> 4;
    const int jc = blockIdx.x & (JC - 1);
    const int i0 = ib * IB;
    const int jbase0 = jc * JPC;

    // stage i-rows into LDS, swizzling 16B column index by (row&7)
    for (int idx = tid; idx < IB * DD / 8; idx += BLK) {
        int row = idx >> 5;
        int c16 = idx & 31;
        short8 v = *(const short8*)(Fb + (size_t)(i0 + row) * DD + c16 * 8);
        *(short8*)(&sFi[row * DD + ((c16 ^ (row & 7)) * 8)]) = v;
    }
    for (int idx = tid; idx < JPC; idx += BLK) slab[idx] = labels[jbase0 + idx];
    __syncthreads();

    int li[4];
#pragma unroll
    for (int it = 0; it < 4; it++) li[it] = labels[i0 + it * 16 + il];

    float sA[4], sB[4], sE1[4], sE2[4], sF1[4], sF2[4], sG[4], sH[4];
#pragma unroll
    for (int it = 0; it < 4; it++) {
        sA[it] = 0.f; sB[it] = 0.f; sE1[it] = 0.f; sE2[it] = 0.f;
        sF1[it] = 0.f; sF2[it] = 0.f; sG[it] = 0.f; sH[it] = 0.f;
    }

    const int swz = il & 7;
    for (int n = 0; n < JT / 8; n++) {
        const int tl = wid + n * 8;
        const int jb = jbase0 + tl * 16;
        const short8* ap = (const short8*)(Fb + (size_t)(jb + il) * DD + kg * 8);
        short8 af[8];
#pragma unroll
        for (int k0 = 0; k0 < 8; k0++) af[k0] = ap[k0 * 4];

        f32x4 acc[4];
#pragma unroll
        for (int it = 0; it < 4; it++) {
            f32x4 c = {0.f, 0.f, 0.f, 0.f};
#pragma unroll
            for (int k0 = 0; k0 < 8; k0++) {
                short8 bf = *(const short8*)(&sFi[(it * 16 + il) * DD + (((kg + k0 * 4) ^ swz) * 8)]);
                c = __builtin_amdgcn_mfma_f32_16x16x32_bf16(af[k0], bf, c, 0, 0, 0);
            }
            acc[it] = c;
        }

        int lj[4];
#pragma unroll
        for (int r = 0; r < 4; r++) lj[r] = slab[tl * 16 + kg * 4 + r];

#pragma unroll
        for (int it = 0; it < 4; it++) {
            const int ig = i0 + it * 16 + il;
#pragma unroll
            for (int r = 0; r < 4; r++) {
                float s = acc[it][r];
                int j = jb + kg * 4 + r;
                bool same = (lj[r] == li[it]);
                float msf = (same && (j != ig)) ? 1.0f : 0.0f;
                float mdf = same ? 0.0f : 1.0f;
                float l = (s - 1.0f) * INV_T;
                float es = __expf(s);
                float el = __expf(l);
                float t = el * es;
                sA[it]  = fmaf(msf, es, sA[it]);
                sB[it]  = fmaf(mdf, es, sB[it]);
                sE1[it] = fmaf(msf, el, sE1[it]);
                sE2[it] = fmaf(mdf, el, sE2[it]);
                sF1[it] = fmaf(msf, t, sF1[it]);
                sF2[it] = fmaf(mdf, t, sF2[it]);
                sG[it]  = fmaf(msf, l, sG[it]);
                sH[it]  = fmaf(msf, l * es, sH[it]);
            }
        }
    }

    // reduce over kg lanes
#pragma unroll
    for (int it = 0; it < 4; it++) {
        sA[it]  += __shfl_xor(sA[it], 16, 64);  sA[it]  += __shfl_xor(sA[it], 32, 64);
        sB[it]  += __shfl_xor(sB[it], 16, 64);  sB[it]  += __shfl_xor(sB[it], 32, 64);
        sE1[it] += __shfl_xor(sE1[it], 16, 64); sE1[it] += __shfl_xor(sE1[it], 32, 64);
        sE2[it] += __shfl_xor(sE2[it], 16, 64); sE2[it] += __shfl_xor(sE2[it], 32, 64);
        sF1[it] += __shfl_xor(sF1[it], 16, 64); sF1[it] += __shfl_xor(sF1[it], 32, 64);
        sF2[it] += __shfl_xor(sF2[it], 16, 64); sF2[it] += __shfl_xor(sF2[it], 32, 64);
        sG[it]  += __shfl_xor(sG[it], 16, 64);  sG[it]  += __shfl_xor(sG[it], 32, 64);
        sH[it]  += __shfl_xor(sH[it], 16, 64);  sH[it]  += __shfl_xor(sH[it], 32, 64);
    }
    __syncthreads();   // done reading sFi; safe to alias as sred
    if (lane < 16) {
#pragma unroll
        for (int it = 0; it < 4; it++) {
            float* p = &sred[(wid * IB + it * 16 + il) * 8];
            p[0] = sA[it];  p[1] = sB[it];  p[2] = sE1[it]; p[3] = sE2[it];
            p[4] = sF1[it]; p[5] = sF2[it]; p[6] = sG[it];  p[7] = sH[it];
        }
    }
    __syncthreads();
    {
        const int row = tid >> 3, k = tid & 7;   // 512 threads = 64 rows x 8 stats
        float v = 0.f;
#pragma unroll
        for (int w = 0; w < 8; w++) v += sred[(w * IB + row) * 8 + k];
        atomicAdd(&gstats[(size_t)(i0 + row) * 8 + k], v);
    }

    // ---- last block finalizes ----
    __threadfence();
    if (tid == 0) {
        unsigned int old = atomicAdd(counter, 1u);
        sdone = (old == GRID - 1) ? 1 : 0;
    }
    __syncthreads();
    if (!sdone) return;

    // label histogram via register counters (labels in 0..9)
    {
        int hc[16];
#pragma unroll
        for (int v = 0; v < 16; v++) hc[v] = 0;
        for (int j = tid; j < NN; j += BLK) {
            int lv = labels[j] & 15;
#pragma unroll
            for (int v = 0; v < 16; v++) hc[v] += (lv == v) ? 1 : 0;
        }
#pragma unroll
        for (int v = 0; v < 16; v++) {
#pragma unroll
            for (int off = 32; off > 0; off >>= 1) hc[v] += __shfl_xor(hc[v], off, 64);
        }
        if (tid < 16) hist[tid] = 0;
        __syncthreads();
        if (lane == 0) {
#pragma unroll
            for (int v = 0; v < 16; v++) atomicAdd(&hist[v], hc[v]);
        }
        __syncthreads();
    }

    float acc = 0.f;
#pragma unroll
    for (int rr = 0; rr < 8; rr++) {
        int i = rr * BLK + tid;
        float st[8];
#pragma unroll
        for (int k = 0; k < 8; k++)
            st[k] = __hip_atomic_load(&gstats[(size_t)i * 8 + k],
                                      __ATOMIC_RELAXED, __HIP_MEMORY_SCOPE_AGENT);
        float a = st[0], b = st[1], e1 = st[2], e2 = st[3];
        float f1 = st[4], f2 = st[5], g = st[6], h = st[7];
        float c = (float)(hist[labels[i] & 15] - 1);
        float As = (a > 0.f) ? a : 1.f;
        float Ad = (b > 0.f) ? b : 1.f;
        float Z = e1 + e2 + f2 / Ad - f1 / As;
        float Q = g - h / As;
        float P = c - a / As;
        float ms = (c > 0.f) ? c : 1.f;
        acc += -(Q - P * logf(Z + 1e-8f)) / ms;
    }
#pragma unroll
    for (int off = 32; off > 0; off >>= 1) acc += __shfl_xor(acc, off, 64);
    if (lane == 0) sacc[wid] = acc;
    __syncthreads();
    if (tid == 0) {
        float t = 0.f;
#pragma unroll
        for (int w = 0; w < 8; w++) t += sacc[w];
        out[0] = t * (1.0f / NN);
    }
}

extern "C" void kernel_launch(void* const* d_in, const int* in_sizes, int n_in,
                              void* d_out, int out_size, void* d_ws, size_t ws_size,
                              hipStream_t stream) {
    const float* F = (const float*)d_in[0];
    const int* labels = (const int*)d_in[1];
    float* out = (float*)d_out;
    unsigned short* Fb = (unsigned short*)d_ws;                       // 2 MB
    float* gstats = (float*)((char*)d_ws + (size_t)NN * DD * 2);      // 128 KB
    unsigned int* counter = (unsigned int*)((char*)d_ws + (size_t)NN * DD * 2 + NSTAT * 4);

    cvt_k<<<NN * DD / 4 / 256, 256, 0, stream>>>(F, Fb, gstats, counter);
    supcon_k<<<GRID, BLK, 0, stream>>>(Fb, labels, gstats, counter, out);
}

// Round 5
// 92.574 us; speedup vs baseline: 2.3526x; 2.3526x over previous
//
#include <hip/hip_runtime.h>

#define NN 4096
#define DD 256
#define TEMP 0.07f
#define INV_T (1.0f / TEMP)
#define BLK 512
#define IB 64            // i-rows per block
#define JC 8             // j-chunks
#define JPC (NN / JC)    // 512 j per chunk
#define JT (JPC / 16)    // 32 j-tiles per chunk; 4 per wave

typedef __attribute__((ext_vector_type(8))) short short8;
typedef __attribute__((ext_vector_type(4))) float f32x4;

__device__ __forceinline__ unsigned short f2bf(float x) {
    unsigned int b = __float_as_uint(x);
    return (unsigned short)((b + 0x7fffu + ((b >> 16) & 1u)) >> 16);
}

// ---------------- convert F f32 -> bf16; zero out ----------------
__global__ __launch_bounds__(256) void cvt_k(const float* __restrict__ F,
                                             unsigned short* __restrict__ Fb,
                                             float* __restrict__ out) {
    int idx = blockIdx.x * 256 + threadIdx.x;
    float4 v = ((const float4*)F)[idx];
    ushort4 o;
    o.x = f2bf(v.x); o.y = f2bf(v.y); o.z = f2bf(v.z); o.w = f2bf(v.w);
    ((ushort4*)Fb)[idx] = o;
    if (idx == 0) out[0] = 0.f;
}

// ---------------- single-pass stats kernel (prefetch-pipelined) ----------------
// 9-sum shift-free decomposition per row i (l=(s-1)/T):
// a=sum_same e^s, b=sum_diff e^s, e1/e2=sum e^l, f1/f2=sum e^l*e^s,
// g=sum_same l, h=sum_same l*e^s.
__global__ __launch_bounds__(BLK, 4) void supcon_k(const unsigned short* __restrict__ Fb,
                                                   const int* __restrict__ labels,
                                                   float* __restrict__ partial) {
    __shared__ unsigned short sFi[IB * DD];   // 32 KB, XOR-swizzled 16B cols
    __shared__ int slab[JPC];                 // 2 KB
    float* sred = (float*)sFi;                // aliased after compute: [8][64][8]

    const int tid = threadIdx.x;
    const int lane = tid & 63;
    const int wid = tid >> 6;
    const int il = lane & 15;
    const int kg = lane >> 4;
    const int ib = blockIdx.x >> 3;
    const int jc = blockIdx.x & 7;
    const int i0 = ib * IB;
    const int jbase0 = jc * JPC;

    // A-fragment base for this lane: tile n lives at  apbase + n*4096 + k0*4  (short8 units)
    // (tile stride = 8 tiles/wave-step * 16 rows * 32 short8/row = 4096)
    const short8* apbase = (const short8*)(Fb + (size_t)(jbase0 + wid * 16 + il) * DD + kg * 8);

    // issue tile-0 A-fragment loads first; they fly during LDS staging
    short8 af[8];
#pragma unroll
    for (int k0 = 0; k0 < 8; k0++) af[k0] = apbase[k0 * 4];

    // stage i-rows into LDS, swizzling 16B column index by (row&7)
    for (int idx = tid; idx < IB * DD / 8; idx += BLK) {
        int row = idx >> 5;
        int c16 = idx & 31;
        short8 v = *(const short8*)(Fb + (size_t)(i0 + row) * DD + c16 * 8);
        *(short8*)(&sFi[row * DD + ((c16 ^ (row & 7)) * 8)]) = v;
    }
    for (int idx = tid; idx < JPC; idx += BLK) slab[idx] = labels[jbase0 + idx];

    int li[4];
#pragma unroll
    for (int it = 0; it < 4; it++) li[it] = labels[i0 + it * 16 + il];

    __syncthreads();

    float sA[4], sB[4], sE1[4], sE2[4], sF1[4], sF2[4], sG[4], sH[4];
#pragma unroll
    for (int it = 0; it < 4; it++) {
        sA[it] = 0.f; sB[it] = 0.f; sE1[it] = 0.f; sE2[it] = 0.f;
        sF1[it] = 0.f; sF2[it] = 0.f; sG[it] = 0.f; sH[it] = 0.f;
    }

    const int swz = il & 7;
#pragma unroll
    for (int n = 0; n < 4; n++) {
        const int tl = wid + n * 8;
        const int jb = jbase0 + tl * 16;

        f32x4 acc[4];
#pragma unroll
        for (int it = 0; it < 4; it++) {
            f32x4 c = {0.f, 0.f, 0.f, 0.f};
#pragma unroll
            for (int k0 = 0; k0 < 8; k0++) {
                short8 bf = *(const short8*)(&sFi[(it * 16 + il) * DD + (((kg + k0 * 4) ^ swz) * 8)]);
                c = __builtin_amdgcn_mfma_f32_16x16x32_bf16(af[k0], bf, c, 0, 0, 0);
            }
            acc[it] = c;
        }

        // prefetch next tile's A-fragments; latency hidden under the epilogue below
        if (n < 3) {
#pragma unroll
            for (int k0 = 0; k0 < 8; k0++) af[k0] = apbase[(n + 1) * 4096 + k0 * 4];
        }

        int lj[4];
#pragma unroll
        for (int r = 0; r < 4; r++) lj[r] = slab[tl * 16 + kg * 4 + r];

#pragma unroll
        for (int it = 0; it < 4; it++) {
            const int ig = i0 + it * 16 + il;
#pragma unroll
            for (int r = 0; r < 4; r++) {
                float s = acc[it][r];
                int j = jb + kg * 4 + r;
                bool same = (lj[r] == li[it]);
                float msf = (same && (j != ig)) ? 1.0f : 0.0f;
                float mdf = same ? 0.0f : 1.0f;
                float l = (s - 1.0f) * INV_T;
                float es = __expf(s);
                float el = __expf(l);
                float t = el * es;
                sA[it]  = fmaf(msf, es, sA[it]);
                sB[it]  = fmaf(mdf, es, sB[it]);
                sE1[it] = fmaf(msf, el, sE1[it]);
                sE2[it] = fmaf(mdf, el, sE2[it]);
                sF1[it] = fmaf(msf, t, sF1[it]);
                sF2[it] = fmaf(mdf, t, sF2[it]);
                sG[it]  = fmaf(msf, l, sG[it]);
                sH[it]  = fmaf(msf, l * es, sH[it]);
            }
        }
    }

    // reduce over kg lanes
#pragma unroll
    for (int it = 0; it < 4; it++) {
        sA[it]  += __shfl_xor(sA[it], 16, 64);  sA[it]  += __shfl_xor(sA[it], 32, 64);
        sB[it]  += __shfl_xor(sB[it], 16, 64);  sB[it]  += __shfl_xor(sB[it], 32, 64);
        sE1[it] += __shfl_xor(sE1[it], 16, 64); sE1[it] += __shfl_xor(sE1[it], 32, 64);
        sE2[it] += __shfl_xor(sE2[it], 16, 64); sE2[it] += __shfl_xor(sE2[it], 32, 64);
        sF1[it] += __shfl_xor(sF1[it], 16, 64); sF1[it] += __shfl_xor(sF1[it], 32, 64);
        sF2[it] += __shfl_xor(sF2[it], 16, 64); sF2[it] += __shfl_xor(sF2[it], 32, 64);
        sG[it]  += __shfl_xor(sG[it], 16, 64);  sG[it]  += __shfl_xor(sG[it], 32, 64);
        sH[it]  += __shfl_xor(sH[it], 16, 64);  sH[it]  += __shfl_xor(sH[it], 32, 64);
    }
    __syncthreads();   // done reading sFi; safe to alias as sred
    if (lane < 16) {
#pragma unroll
        for (int it = 0; it < 4; it++) {
            float* p = &sred[(wid * IB + it * 16 + il) * 8];
            p[0] = sA[it];  p[1] = sB[it];  p[2] = sE1[it]; p[3] = sE2[it];
            p[4] = sF1[it]; p[5] = sF2[it]; p[6] = sG[it];  p[7] = sH[it];
        }
    }
    __syncthreads();
    {
        const int row = tid >> 3, k = tid & 7;   // 512 threads = 64 rows x 8 stats
        float v = 0.f;
#pragma unroll
        for (int w = 0; w < 8; w++) v += sred[(w * IB + row) * 8 + k];
        partial[((size_t)jc * NN + i0 + row) * 8 + k] = v;
    }
}

// ---------------- finalize: merge chunks, compute loss ----------------
__global__ __launch_bounds__(256) void finalize_k(const float* __restrict__ partial,
                                                  const int* __restrict__ labels,
                                                  float* __restrict__ out) {
    __shared__ int hist[16];
    __shared__ float sacc[4];
    const int t = threadIdx.x;
    if (t < 16) hist[t] = 0;
    __syncthreads();
    for (int j = t; j < NN; j += 256) atomicAdd(&hist[labels[j] & 15], 1);
    __syncthreads();

    const int i = blockIdx.x * 256 + t;
    float st[8];
#pragma unroll
    for (int k = 0; k < 8; k++) st[k] = 0.f;
    for (int jc = 0; jc < JC; jc++) {
#pragma unroll
        for (int k = 0; k < 8; k++) st[k] += partial[((size_t)jc * NN + i) * 8 + k];
    }
    float a = st[0], b = st[1], e1 = st[2], e2 = st[3];
    float f1 = st[4], f2 = st[5], g = st[6], h = st[7];
    float c = (float)(hist[labels[i] & 15] - 1);
    float As = (a > 0.f) ? a : 1.f;
    float Ad = (b > 0.f) ? b : 1.f;
    float Z = e1 + e2 + f2 / Ad - f1 / As;
    float Q = g - h / As;
    float P = c - a / As;
    float ms = (c > 0.f) ? c : 1.f;
    float loss_i = -(Q - P * logf(Z + 1e-8f)) / ms;

    float v = loss_i;
#pragma unroll
    for (int off = 32; off > 0; off >>= 1) v += __shfl_xor(v, off, 64);
    if ((t & 63) == 0) sacc[t >> 6] = v;
    __syncthreads();
    if (t == 0) atomicAdd(out, (sacc[0] + sacc[1] + sacc[2] + sacc[3]) * (1.0f / NN));
}

extern "C" void kernel_launch(void* const* d_in, const int* in_sizes, int n_in,
                              void* d_out, int out_size, void* d_ws, size_t ws_size,
                              hipStream_t stream) {
    const float* F = (const float*)d_in[0];
    const int* labels = (const int*)d_in[1];
    float* out = (float*)d_out;
    unsigned short* Fb = (unsigned short*)d_ws;                   // 2 MB
    float* partial = (float*)((char*)d_ws + (size_t)NN * DD * 2); // 1 MB

    cvt_k<<<NN * DD / 4 / 256, 256, 0, stream>>>(F, Fb, out);
    supcon_k<<<(NN / IB) * JC, BLK, 0, stream>>>(Fb, labels, partial);
    finalize_k<<<NN / 256, 256, 0, stream>>>(partial, labels, out);
}

// Round 6
// 91.325 us; speedup vs baseline: 2.3848x; 1.0137x over previous
//
#include <hip/hip_runtime.h>

#define NN 4096
#define DD 256
#define TEMP 0.07f
#define INV_T (1.0f / TEMP)
#define BLK 512
#define IB 64             // i-rows per block (2 tiles of 32)
#define JC 16             // j-chunks
#define JPC (NN / JC)     // 256 j per chunk -> 8 j-tiles of 32, one per wave
#define GRID ((NN / IB) * JC)   // 1024 blocks
#define M_E1 2.718281828f

typedef __attribute__((ext_vector_type(8))) short short8;
typedef __attribute__((ext_vector_type(16))) float f32x16;

__device__ __forceinline__ unsigned short f2bf(float x) {
    unsigned int b = __float_as_uint(x);
    return (unsigned short)((b + 0x7fffu + ((b >> 16) & 1u)) >> 16);
}

// ---------------- convert F f32 -> bf16; zero out ----------------
__global__ __launch_bounds__(256) void cvt_k(const float* __restrict__ F,
                                             unsigned short* __restrict__ Fb,
                                             float* __restrict__ out) {
    int idx = blockIdx.x * 256 + threadIdx.x;
    float4 v = ((const float4*)F)[idx];
    ushort4 o;
    o.x = f2bf(v.x); o.y = f2bf(v.y); o.z = f2bf(v.z); o.w = f2bf(v.w);
    ((ushort4*)Fb)[idx] = o;
    if (idx == 0) out[0] = 0.f;
}

// ---------------- single-pass stats kernel, 32x32x16 MFMA ----------------
// Per row i accumulate 8 stats (l=(s-1)/T):
//   S=sum_all e^s, E=sum_{j!=i} e^l, T=sum_all e^l*e^s,
//   a=sum_same' e^s, f1=sum_same' e^l*e^s, g=sum_same' l, h=sum_same' l*e^s,
//   c=|same'|            (same' = same-label excluding self)
// finalize reconstructs b=S-a-e, f2=T-f1-e (self terms analytic: s_ii~=1).
__global__ __launch_bounds__(BLK, 4) void supcon_k(const unsigned short* __restrict__ Fb,
                                                   const int* __restrict__ labels,
                                                   float* __restrict__ partial) {
    __shared__ unsigned short sFi[IB * DD];   // 32 KB, 32-slot XOR swizzle
    __shared__ int slab[JPC];                 // 1 KB
    float* sred = (float*)sFi;                // aliased after compute: [8][64][8]

    const int tid = threadIdx.x;
    const int lane = tid & 63;
    const int wid = tid >> 6;                 // 0..7 = j-tile
    const int col = lane & 31;                // B col / C col = i-local
    const int hi = lane >> 5;                 // k-half / C row offset
    const int ib = blockIdx.x >> 4;
    const int jc = blockIdx.x & (JC - 1);
    const int i0 = ib * IB;
    const int jb = jc * JPC + wid * 32;       // this wave's j-tile base

    // ---- A-fragment loads first (fly during LDS staging) ----
    // A[row=col_lane][k]: lane holds row=jb+(lane&31), k = kstep*16 + hi*8 .. +8
    const short8* ap = (const short8*)(Fb + (size_t)(jb + col) * DD + hi * 8);
    short8 af[16];
#pragma unroll
    for (int k = 0; k < 16; k++) af[k] = ap[k * 2];

    // ---- stage i-rows into LDS with full 32-slot XOR swizzle ----
    for (int idx = tid; idx < IB * DD / 8; idx += BLK) {
        int row = idx >> 5;
        int c16 = idx & 31;
        short8 v = *(const short8*)(Fb + (size_t)(i0 + row) * DD + c16 * 8);
        *(short8*)(&sFi[row * DD + ((c16 ^ (row & 31)) * 8)]) = v;
    }
    for (int idx = tid; idx < JPC; idx += BLK) slab[idx] = labels[jc * JPC + idx];

    int li[2];
#pragma unroll
    for (int it = 0; it < 2; it++) li[it] = labels[i0 + it * 32 + col];

    __syncthreads();

    // ---- K-loop: 16 steps x {2 LDS b128 reads + 2 MFMA} ----
    f32x16 acc0 = {0.f}, acc1 = {0.f};
#pragma unroll
    for (int r = 0; r < 16; r++) { acc0[r] = 0.f; acc1[r] = 0.f; }
#pragma unroll
    for (int k = 0; k < 16; k++) {
        int slot = (2 * k + hi) ^ col;     // read swizzle: row&31 == col for both tiles
        short8 bf0 = *(const short8*)(&sFi[(col) * DD + slot * 8]);
        short8 bf1 = *(const short8*)(&sFi[(32 + col) * DD + slot * 8]);
        acc0 = __builtin_amdgcn_mfma_f32_32x32x16_bf16(af[k], bf0, acc0, 0, 0, 0);
        acc1 = __builtin_amdgcn_mfma_f32_32x32x16_bf16(af[k], bf1, acc1, 0, 0, 0);
    }

    // ---- epilogue: 8 stats per it ----
    float st0[8], st1[8];
#pragma unroll
    for (int k = 0; k < 8; k++) { st0[k] = 0.f; st1[k] = 0.f; }

#pragma unroll
    for (int r = 0; r < 16; r++) {
        const int row = (r & 3) + 8 * (r >> 2) + 4 * hi;   // C row = j-local
        const int lj = slab[wid * 32 + row];
        const int jg = jb + row;
#pragma unroll
        for (int it = 0; it < 2; it++) {
            float s = (it == 0) ? acc0[r] : acc1[r];
            float* st = (it == 0) ? st0 : st1;
            const int ig = i0 + it * 32 + col;
            bool same = (lj == li[it]);
            bool self = (jg == ig);
            float msf = (same && !self) ? 1.f : 0.f;
            float nsf = self ? 0.f : 1.f;
            float l = (s - 1.f) * INV_T;
            float es = __expf(s);
            float el = __expf(l);
            float t = el * es;
            st[0] += es;                      // S
            st[1] = fmaf(nsf, el, st[1]);     // E (excl self)
            st[2] += t;                       // T
            st[3] = fmaf(msf, es, st[3]);     // a
            st[4] = fmaf(msf, t, st[4]);      // f1
            st[5] = fmaf(msf, l, st[5]);      // g
            st[6] = fmaf(msf, l * es, st[6]); // h
            st[7] += msf;                     // c
        }
    }

    // lanes l and l^32 cover complementary j-rows of the same col: fold
#pragma unroll
    for (int k = 0; k < 8; k++) {
        st0[k] += __shfl_xor(st0[k], 32, 64);
        st1[k] += __shfl_xor(st1[k], 32, 64);
    }

    __syncthreads();   // sFi reads done; alias as sred
    if (lane < 32) {
#pragma unroll
        for (int k = 0; k < 8; k++) {
            sred[((wid * IB) + col) * 8 + k] = st0[k];
            sred[((wid * IB) + 32 + col) * 8 + k] = st1[k];
        }
    }
    __syncthreads();
    {
        const int row = tid >> 3, k = tid & 7;   // 512 threads = 64 rows x 8 stats
        float v = 0.f;
#pragma unroll
        for (int w = 0; w < 8; w++) v += sred[(w * IB + row) * 8 + k];
        partial[((size_t)jc * NN + i0 + row) * 8 + k] = v;
    }
}

// ---------------- finalize: merge chunks, compute loss ----------------
__global__ __launch_bounds__(256) void finalize_k(const float* __restrict__ partial,
                                                  float* __restrict__ out) {
    __shared__ float sacc[4];
    const int t = threadIdx.x;
    const int i = blockIdx.x * 256 + t;

    float st[8];
#pragma unroll
    for (int k = 0; k < 8; k++) st[k] = 0.f;
    for (int jc = 0; jc < JC; jc++) {
#pragma unroll
        for (int k = 0; k < 8; k++) st[k] += partial[((size_t)jc * NN + i) * 8 + k];
    }
    float S = st[0], E = st[1], T = st[2], a = st[3];
    float f1 = st[4], g = st[5], h = st[6], c = st[7];
    float b = S - a - M_E1;             // sum_diff e^s (self term analytic)
    float f2 = T - f1 - M_E1;           // sum_diff e^l e^s
    float As = (a > 0.f) ? a : 1.f;
    float Bd = (b > 0.f) ? b : 1.f;
    float Z = E + f2 / Bd - f1 / As;
    float Q = g - h / As;
    float P = c - ((a > 0.f) ? 1.f : 0.f);
    float ms = (c > 0.f) ? c : 1.f;
    float loss_i = -(Q - P * logf(Z + 1e-8f)) / ms;

    float v = loss_i;
#pragma unroll
    for (int off = 32; off > 0; off >>= 1) v += __shfl_xor(v, off, 64);
    if ((t & 63) == 0) sacc[t >> 6] = v;
    __syncthreads();
    if (t == 0) atomicAdd(out, (sacc[0] + sacc[1] + sacc[2] + sacc[3]) * (1.0f / NN));
}

extern "C" void kernel_launch(void* const* d_in, const int* in_sizes, int n_in,
                              void* d_out, int out_size, void* d_ws, size_t ws_size,
                              hipStream_t stream) {
    const float* F = (const float*)d_in[0];
    const int* labels = (const int*)d_in[1];
    float* out = (float*)d_out;
    unsigned short* Fb = (unsigned short*)d_ws;                   // 2 MB
    float* partial = (float*)((char*)d_ws + (size_t)NN * DD * 2); // 2 MB (JC*NN*8 floats)

    cvt_k<<<NN * DD / 4 / 256, 256, 0, stream>>>(F, Fb, out);
    supcon_k<<<GRID, BLK, 0, stream>>>(Fb, labels, partial);
    finalize_k<<<NN / 256, 256, 0, stream>>>(partial, out);
}